// Round 1
// baseline (2419.177 us; speedup 1.0000x reference)
//
#include <hip/hip_runtime.h>

// Problem constants (from reference): N=50000, E=625000, D=128.
constexpr int D = 128;

// ---------------------------------------------------------------------------
// Scatter-add: agg[dst[e], :] += x[src[e], :]
// 32 lanes per edge, float4 per lane (512 B per edge, coalesced).
// unsafeAtomicAdd -> hardware global_atomic_add_f32 (no CAS loop).
// ---------------------------------------------------------------------------
__global__ void scatter_add_kernel(const float* __restrict__ x,
                                   const int* __restrict__ src,
                                   const int* __restrict__ dst,
                                   float* __restrict__ agg, int E) {
    int tid = blockIdx.x * blockDim.x + threadIdx.x;
    int e = tid >> 5;          // 32 threads per edge
    int lane = tid & 31;
    if (e >= E) return;
    int s = src[e];
    int d = dst[e];
    const float4 v =
        *reinterpret_cast<const float4*>(x + (size_t)s * D + lane * 4);
    float* a = agg + (size_t)d * D + lane * 4;
    unsafeAtomicAdd(a + 0, v.x);
    unsafeAtomicAdd(a + 1, v.y);
    unsafeAtomicAdd(a + 2, v.z);
    unsafeAtomicAdd(a + 3, v.w);
}

// ---------------------------------------------------------------------------
// Fused dual GEMM: out[i,:] = (relu?) (agg[i,:] @ Wrel + brel + hin[i,:] @ Wroot)
// Block = 256 threads handles 16 rows x 128 cols.
// Thread (col, rg) accumulates 8 rows for its column.
// LDS reads are wave-uniform broadcasts (no bank conflicts); W loads are
// coalesced 256B/wave and L1-resident (2 x 64 KB weights reused by all blocks).
// Safe in-place when out == hin: each block stages its own rows to LDS first.
// ---------------------------------------------------------------------------
template <bool RELU>
__global__ void dual_gemm_kernel(const float* __restrict__ agg,
                                 const float* __restrict__ hin,
                                 const float* __restrict__ Wrel,
                                 const float* __restrict__ brel,
                                 const float* __restrict__ Wroot,
                                 float* __restrict__ out, int n) {
    __shared__ float sA[16][D];
    __shared__ float sX[16][D];
    const int row0 = blockIdx.x * 16;
    const int t = threadIdx.x;

    // Stage 16 rows of agg and hin (float4 vectorized, fully coalesced).
    for (int i = t; i < 16 * (D / 4); i += 256) {
        int r = i / (D / 4);
        int c = (i % (D / 4)) * 4;
        int row = row0 + r;
        if (row < n) {
            *reinterpret_cast<float4*>(&sA[r][c]) =
                *reinterpret_cast<const float4*>(agg + (size_t)row * D + c);
            *reinterpret_cast<float4*>(&sX[r][c]) =
                *reinterpret_cast<const float4*>(hin + (size_t)row * D + c);
        }
    }
    __syncthreads();

    const int col = t & (D - 1);
    const int rg = t >> 7;  // 0 or 1 -> rows rg*8 .. rg*8+7
    float acc[8];
#pragma unroll
    for (int r = 0; r < 8; ++r) acc[r] = 0.f;

    for (int k = 0; k < D; ++k) {
        float wr = Wrel[k * D + col];
        float wo = Wroot[k * D + col];
#pragma unroll
        for (int r = 0; r < 8; ++r) {
            int rr = rg * 8 + r;
            acc[r] = fmaf(sA[rr][k], wr, acc[r]);
            acc[r] = fmaf(sX[rr][k], wo, acc[r]);
        }
    }

    const float b = brel[col];
#pragma unroll
    for (int r = 0; r < 8; ++r) {
        int row = row0 + rg * 8 + r;
        if (row < n) {
            float v = acc[r] + b;
            if (RELU) v = fmaxf(v, 0.f);
            out[(size_t)row * D + col] = v;
        }
    }
}

extern "C" void kernel_launch(void* const* d_in, const int* in_sizes, int n_in,
                              void* d_out, int out_size, void* d_ws,
                              size_t ws_size, hipStream_t stream) {
    const float* x      = (const float*)d_in[0];
    const int*   eidx   = (const int*)d_in[1];   // [2, E] flat: src then dst
    const float* W1_rel = (const float*)d_in[2];
    const float* b1_rel = (const float*)d_in[3];
    const float* W1_root= (const float*)d_in[4];
    const float* W2_rel = (const float*)d_in[5];
    const float* b2_rel = (const float*)d_in[6];
    const float* W2_root= (const float*)d_in[7];

    const int n = in_sizes[0] / D;       // 50000
    const int E = in_sizes[1] / 2;       // 625000
    const int* src = eidx;
    const int* dst = eidx + E;

    float* agg = (float*)d_ws;           // N*D fp32 = 25.6 MB
    float* h   = (float*)d_out;          // layer-1 output lives in d_out

    const size_t agg_bytes = (size_t)n * D * sizeof(float);

    const int scatter_threads = 256;
    const int scatter_blocks = (E * 32 + scatter_threads - 1) / scatter_threads;
    const int gemm_blocks = (n + 15) / 16;

    // ---- Layer 1 ----
    hipMemsetAsync(agg, 0, agg_bytes, stream);
    scatter_add_kernel<<<scatter_blocks, scatter_threads, 0, stream>>>(
        x, src, dst, agg, E);
    dual_gemm_kernel<true><<<gemm_blocks, 256, 0, stream>>>(
        agg, x, W1_rel, b1_rel, W1_root, h, n);

    // ---- Layer 2 ----
    hipMemsetAsync(agg, 0, agg_bytes, stream);
    scatter_add_kernel<<<scatter_blocks, scatter_threads, 0, stream>>>(
        h, src, dst, agg, E);
    dual_gemm_kernel<false><<<gemm_blocks, 256, 0, stream>>>(
        agg, h, W2_rel, b2_rel, W2_root, (float*)d_out, n);
}

// Round 2
// 473.185 us; speedup vs baseline: 5.1125x; 5.1125x over previous
//
#include <hip/hip_runtime.h>

// Problem constants (from reference): N=50000, E=625000, D=128.
constexpr int D = 128;

// ===========================================================================
// CSC build (counting sort of edges by dst). Int atomics only (~1.3M total).
// ===========================================================================
__global__ void hist_kernel(const int* __restrict__ dst, int* __restrict__ deg,
                            int E) {
    int i = blockIdx.x * blockDim.x + threadIdx.x;
    if (i < E) atomicAdd(&deg[dst[i]], 1);
}

// Single-block exclusive scan over n counters. deg_cursor: in=degree,
// out=exclusive offset (doubles as the reorder cursor). offs gets the same
// exclusive offsets plus offs[n]=E.
__global__ void scan_kernel(int* __restrict__ deg_cursor, int* __restrict__ offs,
                            int n) {
    __shared__ int tmp[1024];
    __shared__ int carry_s;
    const int t = threadIdx.x;
    if (t == 0) carry_s = 0;
    __syncthreads();
    for (int base = 0; base < n; base += 1024) {
        int i = base + t;
        int v = (i < n) ? deg_cursor[i] : 0;
        tmp[t] = v;
        __syncthreads();
#pragma unroll
        for (int off = 1; off < 1024; off <<= 1) {
            int a = (t >= off) ? tmp[t - off] : 0;
            __syncthreads();
            tmp[t] += a;
            __syncthreads();
        }
        int incl = tmp[t];
        int carry = carry_s;  // stable: last written before a prior barrier
        int excl = incl - v + carry;
        if (i < n) { offs[i] = excl; deg_cursor[i] = excl; }
        __syncthreads();
        if (t == 0) carry_s = carry + tmp[1023];
        __syncthreads();
    }
    if (t == 0) offs[n] = carry_s;
}

__global__ void reorder_kernel(const int* __restrict__ src,
                               const int* __restrict__ dst,
                               int* __restrict__ cursor,
                               int* __restrict__ esrc, int E) {
    int i = blockIdx.x * blockDim.x + threadIdx.x;
    if (i < E) {
        int d = dst[i];
        int p = atomicAdd(&cursor[d], 1);
        esrc[p] = src[i];
    }
}

// ===========================================================================
// Gather-accumulate: agg[g,:] = sum over incoming edges of x[src,:].
// 32 lanes per node, float4 per lane. Pure loads (L2/L3 resident) + FMA,
// zero atomics. Writes every row (zeros for isolated nodes).
// ===========================================================================
__global__ void gather_kernel(const float* __restrict__ x,
                              const int* __restrict__ offs,
                              const int* __restrict__ esrc,
                              float* __restrict__ agg, int n) {
    int tid = blockIdx.x * blockDim.x + threadIdx.x;
    int g = tid >> 5;
    int lane = tid & 31;
    if (g >= n) return;
    int beg = offs[g], end = offs[g + 1];
    float4 acc = {0.f, 0.f, 0.f, 0.f};
    int j = beg;
    for (; j + 1 < end; j += 2) {   // 2-way MLP: both loads issue before adds
        int s0 = esrc[j], s1 = esrc[j + 1];
        const float4 v0 = *reinterpret_cast<const float4*>(x + (size_t)s0 * D + lane * 4);
        const float4 v1 = *reinterpret_cast<const float4*>(x + (size_t)s1 * D + lane * 4);
        acc.x += v0.x; acc.y += v0.y; acc.z += v0.z; acc.w += v0.w;
        acc.x += v1.x; acc.y += v1.y; acc.z += v1.z; acc.w += v1.w;
    }
    if (j < end) {
        int s = esrc[j];
        const float4 v = *reinterpret_cast<const float4*>(x + (size_t)s * D + lane * 4);
        acc.x += v.x; acc.y += v.y; acc.z += v.z; acc.w += v.w;
    }
    *reinterpret_cast<float4*>(agg + (size_t)g * D + lane * 4) = acc;
}

// ===========================================================================
// Fallback scatter (atomic path) — only if ws_size is too small for CSC.
// ===========================================================================
__global__ void scatter_add_kernel(const float* __restrict__ x,
                                   const int* __restrict__ src,
                                   const int* __restrict__ dst,
                                   float* __restrict__ agg, int E) {
    int tid = blockIdx.x * blockDim.x + threadIdx.x;
    int e = tid >> 5;
    int lane = tid & 31;
    if (e >= E) return;
    int s = src[e];
    int d = dst[e];
    const float4 v = *reinterpret_cast<const float4*>(x + (size_t)s * D + lane * 4);
    float* a = agg + (size_t)d * D + lane * 4;
    unsafeAtomicAdd(a + 0, v.x);
    unsafeAtomicAdd(a + 1, v.y);
    unsafeAtomicAdd(a + 2, v.z);
    unsafeAtomicAdd(a + 3, v.w);
}

// ===========================================================================
// Dual GEMM: out[i,:] = (relu?)(agg[i,:] @ Wrel + brel + hin[i,:] @ Wroot)
// Block 256 threads = 32 rows x 128 cols; thread computes 4 rows x 4 cols.
// Per k per thread: 8 ds_read_b32 (broadcast, conflict-free) +
// 2 global dwordx4 (W, L2-hit) + 32 FMA -> VALU-bound.
// Safe in-place when out == hin (rows staged to LDS first, block-local).
// ===========================================================================
template <bool RELU>
__global__ __launch_bounds__(256) void dual_gemm_kernel(
    const float* __restrict__ agg, const float* __restrict__ hin,
    const float* __restrict__ Wrel, const float* __restrict__ brel,
    const float* __restrict__ Wroot, float* __restrict__ out, int n) {
    __shared__ float sA[32][D];
    __shared__ float sX[32][D];
    const int row0 = blockIdx.x * 32;
    const int t = threadIdx.x;

    for (int i = t; i < 32 * (D / 4); i += 256) {
        int r = i >> 5;
        int c = (i & 31) << 2;
        int row = row0 + r;
        float4 za = {0.f, 0.f, 0.f, 0.f};
        float4 zx = {0.f, 0.f, 0.f, 0.f};
        if (row < n) {
            za = *reinterpret_cast<const float4*>(agg + (size_t)row * D + c);
            zx = *reinterpret_cast<const float4*>(hin + (size_t)row * D + c);
        }
        *reinterpret_cast<float4*>(&sA[r][c]) = za;
        *reinterpret_cast<float4*>(&sX[r][c]) = zx;
    }
    __syncthreads();

    const int c4 = (t & 31) << 2;   // column base 0..124
    const int r0 = (t >> 5) << 2;   // row base 0..28
    float acc[4][4];
#pragma unroll
    for (int j = 0; j < 4; ++j)
#pragma unroll
        for (int c = 0; c < 4; ++c) acc[j][c] = 0.f;

    for (int k = 0; k < D; ++k) {
        const float4 wr = *reinterpret_cast<const float4*>(Wrel + k * D + c4);
        const float4 wo = *reinterpret_cast<const float4*>(Wroot + k * D + c4);
#pragma unroll
        for (int j = 0; j < 4; ++j) {
            const float a = sA[r0 + j][k];
            const float xv = sX[r0 + j][k];
            acc[j][0] = fmaf(a, wr.x, acc[j][0]);
            acc[j][1] = fmaf(a, wr.y, acc[j][1]);
            acc[j][2] = fmaf(a, wr.z, acc[j][2]);
            acc[j][3] = fmaf(a, wr.w, acc[j][3]);
            acc[j][0] = fmaf(xv, wo.x, acc[j][0]);
            acc[j][1] = fmaf(xv, wo.y, acc[j][1]);
            acc[j][2] = fmaf(xv, wo.z, acc[j][2]);
            acc[j][3] = fmaf(xv, wo.w, acc[j][3]);
        }
    }

    const float4 b = *reinterpret_cast<const float4*>(brel + c4);
#pragma unroll
    for (int j = 0; j < 4; ++j) {
        int row = row0 + r0 + j;
        if (row < n) {
            float4 v;
            v.x = acc[j][0] + b.x;
            v.y = acc[j][1] + b.y;
            v.z = acc[j][2] + b.z;
            v.w = acc[j][3] + b.w;
            if (RELU) {
                v.x = fmaxf(v.x, 0.f); v.y = fmaxf(v.y, 0.f);
                v.z = fmaxf(v.z, 0.f); v.w = fmaxf(v.w, 0.f);
            }
            *reinterpret_cast<float4*>(out + (size_t)row * D + c4) = v;
        }
    }
}

extern "C" void kernel_launch(void* const* d_in, const int* in_sizes, int n_in,
                              void* d_out, int out_size, void* d_ws,
                              size_t ws_size, hipStream_t stream) {
    const float* x       = (const float*)d_in[0];
    const int*   eidx    = (const int*)d_in[1];  // [2, E] flat: src then dst
    const float* W1_rel  = (const float*)d_in[2];
    const float* b1_rel  = (const float*)d_in[3];
    const float* W1_root = (const float*)d_in[4];
    const float* W2_rel  = (const float*)d_in[5];
    const float* b2_rel  = (const float*)d_in[6];
    const float* W2_root = (const float*)d_in[7];

    const int n = in_sizes[0] / D;  // 50000
    const int E = in_sizes[1] / 2;  // 625000
    const int* src = eidx;
    const int* dst = eidx + E;

    float* agg = (float*)d_ws;                       // N*D fp32 = 25.6 MB
    float* h   = (float*)d_out;                      // layer-1 output in d_out
    const size_t agg_elems = (size_t)n * D;

    const int gemm_blocks = (n + 31) / 32;
    const size_t need = agg_elems * sizeof(float) +
                        (size_t)(n + 1) * sizeof(int) +  // offs
                        (size_t)n * sizeof(int) +        // cursor
                        (size_t)E * sizeof(int);         // esrc

    if (ws_size >= need) {
        // ---- Fast path: CSC build once, atomic-free gathers ----
        int* offs   = (int*)(agg + agg_elems);
        int* cursor = offs + (n + 1);
        int* esrc   = cursor + n;

        hipMemsetAsync(cursor, 0, (size_t)n * sizeof(int), stream);
        hist_kernel<<<(E + 255) / 256, 256, 0, stream>>>(dst, cursor, E);
        scan_kernel<<<1, 1024, 0, stream>>>(cursor, offs, n);
        reorder_kernel<<<(E + 255) / 256, 256, 0, stream>>>(src, dst, cursor,
                                                            esrc, E);

        const int gth_threads = 256;
        const int gth_blocks = (n * 32 + gth_threads - 1) / gth_threads;

        // Layer 1
        gather_kernel<<<gth_blocks, gth_threads, 0, stream>>>(x, offs, esrc,
                                                              agg, n);
        dual_gemm_kernel<true><<<gemm_blocks, 256, 0, stream>>>(
            agg, x, W1_rel, b1_rel, W1_root, h, n);
        // Layer 2
        gather_kernel<<<gth_blocks, gth_threads, 0, stream>>>(h, offs, esrc,
                                                              agg, n);
        dual_gemm_kernel<false><<<gemm_blocks, 256, 0, stream>>>(
            agg, h, W2_rel, b2_rel, W2_root, (float*)d_out, n);
    } else {
        // ---- Fallback: atomic scatter path ----
        const size_t agg_bytes = agg_elems * sizeof(float);
        const int sc_threads = 256;
        const int sc_blocks = (E * 32 + sc_threads - 1) / sc_threads;

        hipMemsetAsync(agg, 0, agg_bytes, stream);
        scatter_add_kernel<<<sc_blocks, sc_threads, 0, stream>>>(x, src, dst,
                                                                 agg, E);
        dual_gemm_kernel<true><<<gemm_blocks, 256, 0, stream>>>(
            agg, x, W1_rel, b1_rel, W1_root, h, n);

        hipMemsetAsync(agg, 0, agg_bytes, stream);
        scatter_add_kernel<<<sc_blocks, sc_threads, 0, stream>>>(h, src, dst,
                                                                 agg, E);
        dual_gemm_kernel<false><<<gemm_blocks, 256, 0, stream>>>(
            agg, h, W2_rel, b2_rel, W2_root, (float*)d_out, n);
    }
}

// Round 3
// 381.324 us; speedup vs baseline: 6.3442x; 1.2409x over previous
//
#include <hip/hip_runtime.h>

// Problem constants (from reference): N=50000, E=625000, D=128.
constexpr int D = 128;
constexpr int SCAN_CHUNK = 1024;  // elements per block in the multi-block scan

// ===========================================================================
// CSC build (counting sort of edges by dst). Int atomics only.
// ===========================================================================
__global__ void hist_kernel(const int* __restrict__ dst, int* __restrict__ deg,
                            int E) {
    int i = blockIdx.x * blockDim.x + threadIdx.x;
    if (i < E) atomicAdd(&deg[dst[i]], 1);
}

// --- Multi-block exclusive scan, phase 1: per-block sums ---
__global__ void block_reduce_kernel(const int* __restrict__ deg,
                                    int* __restrict__ bsums, int n) {
    __shared__ int wsum[4];
    const int t = threadIdx.x;
    const int lane = t & 63, w = t >> 6;
    int base = blockIdx.x * SCAN_CHUNK + t * 4;
    int s = 0;
#pragma unroll
    for (int j = 0; j < 4; ++j)
        if (base + j < n) s += deg[base + j];
#pragma unroll
    for (int off = 32; off > 0; off >>= 1) s += __shfl_down(s, off, 64);
    if (lane == 0) wsum[w] = s;
    __syncthreads();
    if (t == 0) bsums[blockIdx.x] = wsum[0] + wsum[1] + wsum[2] + wsum[3];
}

// --- Phase 2: scan block sums (single wave, carry loop). offs[n] = total. ---
__global__ void scan_bsums_kernel(int* __restrict__ bsums, int nb,
                                  int* __restrict__ offs, int n) {
    const int t = threadIdx.x;  // 64 threads
    int carry = 0;
    for (int base = 0; base < nb; base += 64) {
        int i = base + t;
        int v = (i < nb) ? bsums[i] : 0;
        int incl = v;
#pragma unroll
        for (int off = 1; off < 64; off <<= 1) {
            int u = __shfl_up(incl, off, 64);
            if (t >= off) incl += u;
        }
        if (i < nb) bsums[i] = incl - v + carry;
        carry += __shfl(incl, 63, 64);
    }
    if (t == 0) offs[n] = carry;
}

// --- Phase 3: block-local scan + block offset -> offs[i], cursor[i] ---
__global__ void scan_apply_kernel(const int* __restrict__ bsums,
                                  int* __restrict__ deg_cursor,
                                  int* __restrict__ offs, int n) {
    __shared__ int wsum[4];
    const int t = threadIdx.x;
    const int lane = t & 63, w = t >> 6;
    const int base = blockIdx.x * SCAN_CHUNK + t * 4;
    int v[4];
#pragma unroll
    for (int j = 0; j < 4; ++j)
        v[j] = (base + j < n) ? deg_cursor[base + j] : 0;
    int s = v[0] + v[1] + v[2] + v[3];
    int incl = s;
#pragma unroll
    for (int off = 1; off < 64; off <<= 1) {
        int u = __shfl_up(incl, off, 64);
        if (lane >= off) incl += u;
    }
    if (lane == 63) wsum[w] = incl;
    __syncthreads();
    int woff = 0;
    for (int i = 0; i < w; ++i) woff += wsum[i];
    int excl = incl - s + woff + bsums[blockIdx.x];
#pragma unroll
    for (int j = 0; j < 4; ++j) {
        if (base + j < n) {
            offs[base + j] = excl;
            deg_cursor[base + j] = excl;  // cursor for reorder
        }
        excl += v[j];
    }
}

__global__ void reorder_kernel(const int* __restrict__ src,
                               const int* __restrict__ dst,
                               int* __restrict__ cursor,
                               int* __restrict__ esrc, int E) {
    int i = blockIdx.x * blockDim.x + threadIdx.x;
    if (i < E) {
        int d = dst[i];
        int p = atomicAdd(&cursor[d], 1);
        esrc[p] = src[i];
    }
}

// ===========================================================================
// Gather-accumulate: agg[g,:] = sum over incoming edges of x[src,:].
// 32 lanes per node, float4 per lane, 4-deep ILP. Pure loads + adds.
// ===========================================================================
__global__ void gather_kernel(const float* __restrict__ x,
                              const int* __restrict__ offs,
                              const int* __restrict__ esrc,
                              float* __restrict__ agg, int n) {
    int tid = blockIdx.x * blockDim.x + threadIdx.x;
    int g = tid >> 5;
    int lane = tid & 31;
    if (g >= n) return;
    int beg = offs[g], end = offs[g + 1];
    float4 acc = {0.f, 0.f, 0.f, 0.f};
    int j = beg;
    for (; j + 3 < end; j += 4) {
        int s0 = esrc[j], s1 = esrc[j + 1], s2 = esrc[j + 2], s3 = esrc[j + 3];
        const float4 v0 = *reinterpret_cast<const float4*>(x + (size_t)s0 * D + lane * 4);
        const float4 v1 = *reinterpret_cast<const float4*>(x + (size_t)s1 * D + lane * 4);
        const float4 v2 = *reinterpret_cast<const float4*>(x + (size_t)s2 * D + lane * 4);
        const float4 v3 = *reinterpret_cast<const float4*>(x + (size_t)s3 * D + lane * 4);
        acc.x += v0.x; acc.y += v0.y; acc.z += v0.z; acc.w += v0.w;
        acc.x += v1.x; acc.y += v1.y; acc.z += v1.z; acc.w += v1.w;
        acc.x += v2.x; acc.y += v2.y; acc.z += v2.z; acc.w += v2.w;
        acc.x += v3.x; acc.y += v3.y; acc.z += v3.z; acc.w += v3.w;
    }
    for (; j < end; ++j) {
        int s = esrc[j];
        const float4 v = *reinterpret_cast<const float4*>(x + (size_t)s * D + lane * 4);
        acc.x += v.x; acc.y += v.y; acc.z += v.z; acc.w += v.w;
    }
    *reinterpret_cast<float4*>(agg + (size_t)g * D + lane * 4) = acc;
}

// ===========================================================================
// Fallback scatter (atomic path) — only if ws_size is too small for CSC.
// ===========================================================================
__global__ void scatter_add_kernel(const float* __restrict__ x,
                                   const int* __restrict__ src,
                                   const int* __restrict__ dst,
                                   float* __restrict__ agg, int E) {
    int tid = blockIdx.x * blockDim.x + threadIdx.x;
    int e = tid >> 5;
    int lane = tid & 31;
    if (e >= E) return;
    int s = src[e];
    int d = dst[e];
    const float4 v = *reinterpret_cast<const float4*>(x + (size_t)s * D + lane * 4);
    float* a = agg + (size_t)d * D + lane * 4;
    unsafeAtomicAdd(a + 0, v.x);
    unsafeAtomicAdd(a + 1, v.y);
    unsafeAtomicAdd(a + 2, v.z);
    unsafeAtomicAdd(a + 3, v.w);
}

// ===========================================================================
// Dual GEMM: out[i,:] = (relu?)(agg[i,:] @ Wrel + brel + hin[i,:] @ Wroot)
// Block 256 threads = 32 rows x 128 cols; thread computes 4 rows x 4 cols.
// Safe in-place when out == hin (rows staged to LDS first, block-local).
// ===========================================================================
template <bool RELU>
__global__ __launch_bounds__(256) void dual_gemm_kernel(
    const float* __restrict__ agg, const float* __restrict__ hin,
    const float* __restrict__ Wrel, const float* __restrict__ brel,
    const float* __restrict__ Wroot, float* __restrict__ out, int n) {
    __shared__ float sA[32][D];
    __shared__ float sX[32][D];
    const int row0 = blockIdx.x * 32;
    const int t = threadIdx.x;

    for (int i = t; i < 32 * (D / 4); i += 256) {
        int r = i >> 5;
        int c = (i & 31) << 2;
        int row = row0 + r;
        float4 za = {0.f, 0.f, 0.f, 0.f};
        float4 zx = {0.f, 0.f, 0.f, 0.f};
        if (row < n) {
            za = *reinterpret_cast<const float4*>(agg + (size_t)row * D + c);
            zx = *reinterpret_cast<const float4*>(hin + (size_t)row * D + c);
        }
        *reinterpret_cast<float4*>(&sA[r][c]) = za;
        *reinterpret_cast<float4*>(&sX[r][c]) = zx;
    }
    __syncthreads();

    const int c4 = (t & 31) << 2;   // column base 0..124
    const int r0 = (t >> 5) << 2;   // row base 0..28
    float acc[4][4];
#pragma unroll
    for (int j = 0; j < 4; ++j)
#pragma unroll
        for (int c = 0; c < 4; ++c) acc[j][c] = 0.f;

    for (int k = 0; k < D; ++k) {
        const float4 wr = *reinterpret_cast<const float4*>(Wrel + k * D + c4);
        const float4 wo = *reinterpret_cast<const float4*>(Wroot + k * D + c4);
#pragma unroll
        for (int j = 0; j < 4; ++j) {
            const float a = sA[r0 + j][k];
            const float xv = sX[r0 + j][k];
            acc[j][0] = fmaf(a, wr.x, acc[j][0]);
            acc[j][1] = fmaf(a, wr.y, acc[j][1]);
            acc[j][2] = fmaf(a, wr.z, acc[j][2]);
            acc[j][3] = fmaf(a, wr.w, acc[j][3]);
            acc[j][0] = fmaf(xv, wo.x, acc[j][0]);
            acc[j][1] = fmaf(xv, wo.y, acc[j][1]);
            acc[j][2] = fmaf(xv, wo.z, acc[j][2]);
            acc[j][3] = fmaf(xv, wo.w, acc[j][3]);
        }
    }

    const float4 b = *reinterpret_cast<const float4*>(brel + c4);
#pragma unroll
    for (int j = 0; j < 4; ++j) {
        int row = row0 + r0 + j;
        if (row < n) {
            float4 v;
            v.x = acc[j][0] + b.x;
            v.y = acc[j][1] + b.y;
            v.z = acc[j][2] + b.z;
            v.w = acc[j][3] + b.w;
            if (RELU) {
                v.x = fmaxf(v.x, 0.f); v.y = fmaxf(v.y, 0.f);
                v.z = fmaxf(v.z, 0.f); v.w = fmaxf(v.w, 0.f);
            }
            *reinterpret_cast<float4*>(out + (size_t)row * D + c4) = v;
        }
    }
}

extern "C" void kernel_launch(void* const* d_in, const int* in_sizes, int n_in,
                              void* d_out, int out_size, void* d_ws,
                              size_t ws_size, hipStream_t stream) {
    const float* x       = (const float*)d_in[0];
    const int*   eidx    = (const int*)d_in[1];  // [2, E] flat: src then dst
    const float* W1_rel  = (const float*)d_in[2];
    const float* b1_rel  = (const float*)d_in[3];
    const float* W1_root = (const float*)d_in[4];
    const float* W2_rel  = (const float*)d_in[5];
    const float* b2_rel  = (const float*)d_in[6];
    const float* W2_root = (const float*)d_in[7];

    const int n = in_sizes[0] / D;  // 50000
    const int E = in_sizes[1] / 2;  // 625000
    const int* src = eidx;
    const int* dst = eidx + E;

    float* agg = (float*)d_ws;                       // N*D fp32 = 25.6 MB
    float* h   = (float*)d_out;                      // layer-1 output in d_out
    const size_t agg_elems = (size_t)n * D;

    const int gemm_blocks = (n + 31) / 32;
    const int nb = (n + SCAN_CHUNK - 1) / SCAN_CHUNK;  // scan blocks
    const size_t need = agg_elems * sizeof(float) +
                        (size_t)(n + 1) * sizeof(int) +  // offs
                        (size_t)n * sizeof(int) +        // cursor
                        (size_t)E * sizeof(int) +        // esrc
                        (size_t)nb * sizeof(int);        // bsums

    if (ws_size >= need) {
        // ---- Fast path: CSC build once, atomic-free gathers ----
        int* offs   = (int*)(agg + agg_elems);
        int* cursor = offs + (n + 1);
        int* esrc   = cursor + n;
        int* bsums  = esrc + E;

        hipMemsetAsync(cursor, 0, (size_t)n * sizeof(int), stream);
        hist_kernel<<<(E + 255) / 256, 256, 0, stream>>>(dst, cursor, E);
        block_reduce_kernel<<<nb, 256, 0, stream>>>(cursor, bsums, n);
        scan_bsums_kernel<<<1, 64, 0, stream>>>(bsums, nb, offs, n);
        scan_apply_kernel<<<nb, 256, 0, stream>>>(bsums, cursor, offs, n);
        reorder_kernel<<<(E + 255) / 256, 256, 0, stream>>>(src, dst, cursor,
                                                            esrc, E);

        const int gth_threads = 256;
        const int gth_blocks = (n * 32 + gth_threads - 1) / gth_threads;

        // Layer 1
        gather_kernel<<<gth_blocks, gth_threads, 0, stream>>>(x, offs, esrc,
                                                              agg, n);
        dual_gemm_kernel<true><<<gemm_blocks, 256, 0, stream>>>(
            agg, x, W1_rel, b1_rel, W1_root, h, n);
        // Layer 2
        gather_kernel<<<gth_blocks, gth_threads, 0, stream>>>(h, offs, esrc,
                                                              agg, n);
        dual_gemm_kernel<false><<<gemm_blocks, 256, 0, stream>>>(
            agg, h, W2_rel, b2_rel, W2_root, (float*)d_out, n);
    } else {
        // ---- Fallback: atomic scatter path ----
        const size_t agg_bytes = agg_elems * sizeof(float);
        const int sc_threads = 256;
        const int sc_blocks = (E * 32 + sc_threads - 1) / sc_threads;

        hipMemsetAsync(agg, 0, agg_bytes, stream);
        scatter_add_kernel<<<sc_blocks, sc_threads, 0, stream>>>(x, src, dst,
                                                                 agg, E);
        dual_gemm_kernel<true><<<gemm_blocks, 256, 0, stream>>>(
            agg, x, W1_rel, b1_rel, W1_root, h, n);

        hipMemsetAsync(agg, 0, agg_bytes, stream);
        scatter_add_kernel<<<sc_blocks, sc_threads, 0, stream>>>(h, src, dst,
                                                                 agg, E);
        dual_gemm_kernel<false><<<gemm_blocks, 256, 0, stream>>>(
            agg, h, W2_rel, b2_rel, W2_root, (float*)d_out, n);
    }
}

// Round 4
// 249.513 us; speedup vs baseline: 9.6956x; 1.5283x over previous
//
#include <hip/hip_runtime.h>

// Problem constants (from reference): N=50000, E=625000, D=128.
constexpr int D = 128;
constexpr int SCAN_CHUNK = 1024;

using short8 = __attribute__((ext_vector_type(8))) short;
using f32x4  = __attribute__((ext_vector_type(4))) float;

// RNE float -> bf16 (finite inputs).
__device__ inline unsigned short f2bf(float f) {
    union { float f; unsigned u; } un;
    un.f = f;
    unsigned u = un.u;
    return (unsigned short)((u + 0x7fffu + ((u >> 16) & 1u)) >> 16);
}

// ===========================================================================
// CSC build (counting sort of edges by dst). Int atomics only.
// ===========================================================================
__global__ void hist_kernel(const int* __restrict__ dst, int* __restrict__ deg,
                            int E) {
    int i = blockIdx.x * blockDim.x + threadIdx.x;
    if (i < E) atomicAdd(&deg[dst[i]], 1);
}

__global__ void block_reduce_kernel(const int* __restrict__ deg,
                                    int* __restrict__ bsums, int n) {
    __shared__ int wsum[4];
    const int t = threadIdx.x;
    const int lane = t & 63, w = t >> 6;
    int base = blockIdx.x * SCAN_CHUNK + t * 4;
    int s = 0;
#pragma unroll
    for (int j = 0; j < 4; ++j)
        if (base + j < n) s += deg[base + j];
#pragma unroll
    for (int off = 32; off > 0; off >>= 1) s += __shfl_down(s, off, 64);
    if (lane == 0) wsum[w] = s;
    __syncthreads();
    if (t == 0) bsums[blockIdx.x] = wsum[0] + wsum[1] + wsum[2] + wsum[3];
}

__global__ void scan_bsums_kernel(int* __restrict__ bsums, int nb,
                                  int* __restrict__ offs, int n) {
    const int t = threadIdx.x;  // 64 threads
    int carry = 0;
    for (int base = 0; base < nb; base += 64) {
        int i = base + t;
        int v = (i < nb) ? bsums[i] : 0;
        int incl = v;
#pragma unroll
        for (int off = 1; off < 64; off <<= 1) {
            int u = __shfl_up(incl, off, 64);
            if (t >= off) incl += u;
        }
        if (i < nb) bsums[i] = incl - v + carry;
        carry += __shfl(incl, 63, 64);
    }
    if (t == 0) offs[n] = carry;
}

__global__ void scan_apply_kernel(const int* __restrict__ bsums,
                                  int* __restrict__ deg_cursor,
                                  int* __restrict__ offs, int n) {
    __shared__ int wsum[4];
    const int t = threadIdx.x;
    const int lane = t & 63, w = t >> 6;
    const int base = blockIdx.x * SCAN_CHUNK + t * 4;
    int v[4];
#pragma unroll
    for (int j = 0; j < 4; ++j)
        v[j] = (base + j < n) ? deg_cursor[base + j] : 0;
    int s = v[0] + v[1] + v[2] + v[3];
    int incl = s;
#pragma unroll
    for (int off = 1; off < 64; off <<= 1) {
        int u = __shfl_up(incl, off, 64);
        if (lane >= off) incl += u;
    }
    if (lane == 63) wsum[w] = incl;
    __syncthreads();
    int woff = 0;
    for (int i = 0; i < w; ++i) woff += wsum[i];
    int excl = incl - s + woff + bsums[blockIdx.x];
#pragma unroll
    for (int j = 0; j < 4; ++j) {
        if (base + j < n) {
            offs[base + j] = excl;
            deg_cursor[base + j] = excl;
        }
        excl += v[j];
    }
}

__global__ void reorder_kernel(const int* __restrict__ src,
                               const int* __restrict__ dst,
                               int* __restrict__ cursor,
                               int* __restrict__ esrc, int E) {
    int i = blockIdx.x * blockDim.x + threadIdx.x;
    if (i < E) {
        int d = dst[i];
        int p = atomicAdd(&cursor[d], 1);
        esrc[p] = src[i];
    }
}

// ===========================================================================
// fp32 -> bf16 bulk convert (4 elems/thread).
// ===========================================================================
__global__ void f32_to_bf16_kernel(const float* __restrict__ in,
                                   unsigned short* __restrict__ out,
                                   int nelem) {
    int i = (blockIdx.x * blockDim.x + threadIdx.x) * 4;
    if (i >= nelem) return;
    float4 v = *reinterpret_cast<const float4*>(in + i);
    unsigned short o[4];
    o[0] = f2bf(v.x); o[1] = f2bf(v.y); o[2] = f2bf(v.z); o[3] = f2bf(v.w);
    *reinterpret_cast<uint2*>(out + i) = *reinterpret_cast<uint2*>(o);
}

// ===========================================================================
// Build swizzled B (weights) in MFMA B-fragment order, bf16.
// Bswz[((qq*8 + t)*64 + lane)*8 + j] = Wcat[qq*32 + (lane>>4)*8 + j][t*16 + (lane&15)]
// where Wcat rows 0-127 = W_rel, 128-255 = W_root. One thread per (qq,t,lane).
// ===========================================================================
__global__ void build_bswz_kernel(const float* __restrict__ Wrel,
                                  const float* __restrict__ Wroot,
                                  unsigned short* __restrict__ bswz) {
    int idx = blockIdx.x * blockDim.x + threadIdx.x;  // 0..4095
    if (idx >= 8 * 8 * 64) return;
    int lane = idx & 63;
    int t = (idx >> 6) & 7;
    int qq = idx >> 9;
    int col = t * 16 + (lane & 15);
    const float* W = (qq < 4) ? Wrel : Wroot;
    int kbase = (qq & 3) * 32 + ((lane >> 4) * 8);
    unsigned short o[8];
#pragma unroll
    for (int j = 0; j < 8; ++j) o[j] = f2bf(W[(size_t)(kbase + j) * D + col]);
    *reinterpret_cast<uint4*>(bswz + (size_t)idx * 8) =
        *reinterpret_cast<uint4*>(o);
}

// ===========================================================================
// bf16 gather-accumulate: aggb[g,:] = bf16( sum_{e in N(g)} f32(xb[src_e,:]) )
// 16 lanes per node, 8 bf16 (16B) per lane, fp32 accumulation, 4-deep ILP.
// ===========================================================================
__device__ inline void add8(float* acc, uint4 v) {
    const unsigned u0 = v.x, u1 = v.y, u2 = v.z, u3 = v.w;
    acc[0] += __uint_as_float(u0 << 16);
    acc[1] += __uint_as_float(u0 & 0xffff0000u);
    acc[2] += __uint_as_float(u1 << 16);
    acc[3] += __uint_as_float(u1 & 0xffff0000u);
    acc[4] += __uint_as_float(u2 << 16);
    acc[5] += __uint_as_float(u2 & 0xffff0000u);
    acc[6] += __uint_as_float(u3 << 16);
    acc[7] += __uint_as_float(u3 & 0xffff0000u);
}

__global__ void gather_bf16_kernel(const unsigned short* __restrict__ xb,
                                   const int* __restrict__ offs,
                                   const int* __restrict__ esrc,
                                   unsigned short* __restrict__ aggb, int n) {
    int tid = blockIdx.x * blockDim.x + threadIdx.x;
    int g = tid >> 4;
    int lane = tid & 15;
    if (g >= n) return;
    int beg = offs[g], end = offs[g + 1];
    float acc[8] = {0.f, 0.f, 0.f, 0.f, 0.f, 0.f, 0.f, 0.f};
    int j = beg;
    for (; j + 3 < end; j += 4) {
        int s0 = esrc[j], s1 = esrc[j + 1], s2 = esrc[j + 2], s3 = esrc[j + 3];
        uint4 v0 = *reinterpret_cast<const uint4*>(xb + (size_t)s0 * D + lane * 8);
        uint4 v1 = *reinterpret_cast<const uint4*>(xb + (size_t)s1 * D + lane * 8);
        uint4 v2 = *reinterpret_cast<const uint4*>(xb + (size_t)s2 * D + lane * 8);
        uint4 v3 = *reinterpret_cast<const uint4*>(xb + (size_t)s3 * D + lane * 8);
        add8(acc, v0); add8(acc, v1); add8(acc, v2); add8(acc, v3);
    }
    for (; j < end; ++j) {
        int s = esrc[j];
        uint4 v = *reinterpret_cast<const uint4*>(xb + (size_t)s * D + lane * 8);
        add8(acc, v);
    }
    unsigned short o[8];
#pragma unroll
    for (int i = 0; i < 8; ++i) o[i] = f2bf(acc[i]);
    *reinterpret_cast<uint4*>(aggb + (size_t)g * D + lane * 8) =
        *reinterpret_cast<uint4*>(o);
}

// ===========================================================================
// MFMA GEMM: out[i,:] = (relu?)( Ab[i,:] @ Wrel + bias + Xb[i,:] @ Wroot )
// K = 256 (half 0: Ab x Wrel, half 1: Xb x Wroot), all bf16 inputs, fp32 acc.
// Block = 256 thr = 4 waves; wave covers 32 rows x 128 cols (2x8 MFMA tiles).
// No LDS, no barriers: A-frags are 16B row-contiguous loads; B-frags come from
// the pre-swizzled global Bswz (L2-hot, reused by every wave).
// mfma_f32_16x16x32_bf16 layouts (verified, learn_hip m89/m91/m120):
//   A: lane=(quad,m): A[m=lane&15][k=quad*8+j]
//   B: lane=(quad,n): B[k=quad*8+j][n=lane&15]
//   C/D: reg i: row=quad*4+i, col=lane&15
// ===========================================================================
template <bool RELU, bool OUT_BF16>
__global__ __launch_bounds__(256) void mfma_gemm_kernel(
    const unsigned short* __restrict__ Ab, const unsigned short* __restrict__ Xb,
    const unsigned short* __restrict__ Bswz, const float* __restrict__ bias,
    unsigned short* __restrict__ outb, float* __restrict__ outf, int n) {
    const int t = threadIdx.x;
    const int lane = t & 63;
    const int w = t >> 6;
    const int quad = lane >> 4;
    const int l15 = lane & 15;
    const int R0 = blockIdx.x * 128 + w * 32;  // wave's 32 rows

    f32x4 acc[2][8];
#pragma unroll
    for (int rt = 0; rt < 2; ++rt)
#pragma unroll
        for (int nt = 0; nt < 8; ++nt)
            acc[rt][nt] = f32x4{0.f, 0.f, 0.f, 0.f};

    int rowA0 = R0 + l15;
    int rowA1 = R0 + 16 + l15;
    rowA0 = (rowA0 < n) ? rowA0 : (n - 1);  // clamp: OOB rows never stored
    rowA1 = (rowA1 < n) ? rowA1 : (n - 1);

    for (int qq = 0; qq < 8; ++qq) {
        const unsigned short* Asrc = (qq < 4) ? Ab : Xb;
        const int kb = (qq & 3) * 32 + quad * 8;
        short8 a0 = *reinterpret_cast<const short8*>(Asrc + (size_t)rowA0 * D + kb);
        short8 a1 = *reinterpret_cast<const short8*>(Asrc + (size_t)rowA1 * D + kb);
        const unsigned short* bp = Bswz + ((size_t)(qq * 8) * 64 + lane) * 8;
#pragma unroll
        for (int nt = 0; nt < 8; ++nt) {
            short8 b = *reinterpret_cast<const short8*>(bp + (size_t)nt * 64 * 8);
            acc[0][nt] = __builtin_amdgcn_mfma_f32_16x16x32_bf16(a0, b, acc[0][nt], 0, 0, 0);
            acc[1][nt] = __builtin_amdgcn_mfma_f32_16x16x32_bf16(a1, b, acc[1][nt], 0, 0, 0);
        }
    }

#pragma unroll
    for (int nt = 0; nt < 8; ++nt) {
        const int col = nt * 16 + l15;
        const float bv = bias[col];
#pragma unroll
        for (int rt = 0; rt < 2; ++rt) {
#pragma unroll
            for (int i = 0; i < 4; ++i) {
                int row = R0 + rt * 16 + quad * 4 + i;
                if (row < n) {
                    float v = acc[rt][nt][i] + bv;
                    if (RELU) v = fmaxf(v, 0.f);
                    if (OUT_BF16) outb[(size_t)row * D + col] = f2bf(v);
                    else outf[(size_t)row * D + col] = v;
                }
            }
        }
    }
}

// ===========================================================================
// Fallback (atomic scatter + fp32 VALU GEMM) — only if ws is too small.
// ===========================================================================
__global__ void scatter_add_kernel(const float* __restrict__ x,
                                   const int* __restrict__ src,
                                   const int* __restrict__ dst,
                                   float* __restrict__ agg, int E) {
    int tid = blockIdx.x * blockDim.x + threadIdx.x;
    int e = tid >> 5;
    int lane = tid & 31;
    if (e >= E) return;
    int s = src[e];
    int d = dst[e];
    const float4 v = *reinterpret_cast<const float4*>(x + (size_t)s * D + lane * 4);
    float* a = agg + (size_t)d * D + lane * 4;
    unsafeAtomicAdd(a + 0, v.x);
    unsafeAtomicAdd(a + 1, v.y);
    unsafeAtomicAdd(a + 2, v.z);
    unsafeAtomicAdd(a + 3, v.w);
}

template <bool RELU>
__global__ __launch_bounds__(256) void dual_gemm_kernel(
    const float* __restrict__ agg, const float* __restrict__ hin,
    const float* __restrict__ Wrel, const float* __restrict__ brel,
    const float* __restrict__ Wroot, float* __restrict__ out, int n) {
    __shared__ float sA[32][D];
    __shared__ float sX[32][D];
    const int row0 = blockIdx.x * 32;
    const int t = threadIdx.x;
    for (int i = t; i < 32 * (D / 4); i += 256) {
        int r = i >> 5;
        int c = (i & 31) << 2;
        int row = row0 + r;
        float4 za = {0.f, 0.f, 0.f, 0.f};
        float4 zx = {0.f, 0.f, 0.f, 0.f};
        if (row < n) {
            za = *reinterpret_cast<const float4*>(agg + (size_t)row * D + c);
            zx = *reinterpret_cast<const float4*>(hin + (size_t)row * D + c);
        }
        *reinterpret_cast<float4*>(&sA[r][c]) = za;
        *reinterpret_cast<float4*>(&sX[r][c]) = zx;
    }
    __syncthreads();
    const int c4 = (t & 31) << 2;
    const int r0 = (t >> 5) << 2;
    float acc[4][4];
#pragma unroll
    for (int j = 0; j < 4; ++j)
#pragma unroll
        for (int c = 0; c < 4; ++c) acc[j][c] = 0.f;
    for (int k = 0; k < D; ++k) {
        const float4 wr = *reinterpret_cast<const float4*>(Wrel + k * D + c4);
        const float4 wo = *reinterpret_cast<const float4*>(Wroot + k * D + c4);
#pragma unroll
        for (int j = 0; j < 4; ++j) {
            const float a = sA[r0 + j][k];
            const float xv = sX[r0 + j][k];
            acc[j][0] = fmaf(a, wr.x, acc[j][0]);
            acc[j][1] = fmaf(a, wr.y, acc[j][1]);
            acc[j][2] = fmaf(a, wr.z, acc[j][2]);
            acc[j][3] = fmaf(a, wr.w, acc[j][3]);
            acc[j][0] = fmaf(xv, wo.x, acc[j][0]);
            acc[j][1] = fmaf(xv, wo.y, acc[j][1]);
            acc[j][2] = fmaf(xv, wo.z, acc[j][2]);
            acc[j][3] = fmaf(xv, wo.w, acc[j][3]);
        }
    }
    const float4 b = *reinterpret_cast<const float4*>(brel + c4);
#pragma unroll
    for (int j = 0; j < 4; ++j) {
        int row = row0 + r0 + j;
        if (row < n) {
            float4 v;
            v.x = acc[j][0] + b.x;
            v.y = acc[j][1] + b.y;
            v.z = acc[j][2] + b.z;
            v.w = acc[j][3] + b.w;
            if (RELU) {
                v.x = fmaxf(v.x, 0.f); v.y = fmaxf(v.y, 0.f);
                v.z = fmaxf(v.z, 0.f); v.w = fmaxf(v.w, 0.f);
            }
            *reinterpret_cast<float4*>(out + (size_t)row * D + c4) = v;
        }
    }
}

extern "C" void kernel_launch(void* const* d_in, const int* in_sizes, int n_in,
                              void* d_out, int out_size, void* d_ws,
                              size_t ws_size, hipStream_t stream) {
    const float* x       = (const float*)d_in[0];
    const int*   eidx    = (const int*)d_in[1];  // [2, E] flat: src then dst
    const float* W1_rel  = (const float*)d_in[2];
    const float* b1_rel  = (const float*)d_in[3];
    const float* W1_root = (const float*)d_in[4];
    const float* W2_rel  = (const float*)d_in[5];
    const float* b2_rel  = (const float*)d_in[6];
    const float* W2_root = (const float*)d_in[7];

    const int n = in_sizes[0] / D;  // 50000
    const int E = in_sizes[1] / 2;  // 625000
    const int* src = eidx;
    const int* dst = eidx + E;

    const int nb = (n + SCAN_CHUNK - 1) / SCAN_CHUNK;
    const size_t feat = (size_t)n * D;  // 6.4M elements

    // ws layout (bf16 path): xb | hb | aggb | bswz1 | bswz2 | offs | cursor | esrc | bsums
    const size_t need = feat * 2 * 3 + 65536 * 2 * 2 +
                        ((size_t)(n + 1) + n + E + nb) * sizeof(int);

    if (ws_size >= need) {
        unsigned short* xb    = (unsigned short*)d_ws;
        unsigned short* hb    = xb + feat;
        unsigned short* aggb  = hb + feat;
        unsigned short* bswz1 = aggb + feat;
        unsigned short* bswz2 = bswz1 + 8 * 8 * 64 * 8;  // 32768 ushorts
        int* offs   = (int*)(bswz2 + 8 * 8 * 64 * 8);
        int* cursor = offs + (n + 1);
        int* esrc   = cursor + n;
        // bsums after esrc
        int* bsums  = esrc + E;

        // --- CSC build ---
        hipMemsetAsync(cursor, 0, (size_t)n * sizeof(int), stream);
        hist_kernel<<<(E + 255) / 256, 256, 0, stream>>>(dst, cursor, E);
        block_reduce_kernel<<<nb, 256, 0, stream>>>(cursor, bsums, n);
        scan_bsums_kernel<<<1, 64, 0, stream>>>(bsums, nb, offs, n);
        scan_apply_kernel<<<nb, 256, 0, stream>>>(bsums, cursor, offs, n);
        reorder_kernel<<<(E + 255) / 256, 256, 0, stream>>>(src, dst, cursor,
                                                            esrc, E);

        // --- Conversions (independent of CSC) ---
        f32_to_bf16_kernel<<<((int)feat / 4 + 255) / 256, 256, 0, stream>>>(
            x, xb, (int)feat);
        build_bswz_kernel<<<16, 256, 0, stream>>>(W1_rel, W1_root, bswz1);
        build_bswz_kernel<<<16, 256, 0, stream>>>(W2_rel, W2_root, bswz2);

        const int gth_blocks = (n * 16 + 255) / 256;
        const int gemm_blocks = (n + 127) / 128;

        // --- Layer 1 ---
        gather_bf16_kernel<<<gth_blocks, 256, 0, stream>>>(xb, offs, esrc,
                                                           aggb, n);
        mfma_gemm_kernel<true, true><<<gemm_blocks, 256, 0, stream>>>(
            aggb, xb, bswz1, b1_rel, hb, nullptr, n);
        // --- Layer 2 ---
        gather_bf16_kernel<<<gth_blocks, 256, 0, stream>>>(hb, offs, esrc,
                                                           aggb, n);
        mfma_gemm_kernel<false, false><<<gemm_blocks, 256, 0, stream>>>(
            aggb, hb, bswz2, b2_rel, nullptr, (float*)d_out, n);
    } else {
        // --- Fallback: atomic scatter + fp32 VALU GEMM ---
        float* agg = (float*)d_ws;  // N*D fp32
        float* h   = (float*)d_out;
        const size_t agg_bytes = feat * sizeof(float);
        const int sc_blocks = (E * 32 + 255) / 256;
        const int gemm_blocks = (n + 31) / 32;

        hipMemsetAsync(agg, 0, agg_bytes, stream);
        scatter_add_kernel<<<sc_blocks, 256, 0, stream>>>(x, src, dst, agg, E);
        dual_gemm_kernel<true><<<gemm_blocks, 256, 0, stream>>>(
            agg, x, W1_rel, b1_rel, W1_root, h, n);

        hipMemsetAsync(agg, 0, agg_bytes, stream);
        scatter_add_kernel<<<sc_blocks, 256, 0, stream>>>(h, src, dst, agg, E);
        dual_gemm_kernel<false><<<gemm_blocks, 256, 0, stream>>>(
            agg, h, W2_rel, b2_rel, W2_root, (float*)d_out, n);
    }
}